// Round 1
// baseline (764.606 us; speedup 1.0000x reference)
//
#include <hip/hip_runtime.h>
#include <hip/hip_cooperative_groups.h>
#include <math.h>

namespace cg = cooperative_groups;

// Problem constants (fixed by setup_inputs)
#define BSZ    2
#define LFULL  4096
#define MLEN   2048      // M = hidden_states.shape[1]
#define DMODEL 2048
#define CLIP_EPS 1e-4f
#define CCH    256       // number of chunks
#define TCH    8         // chunk length; CCH*TCH == MLEN

typedef float f4 __attribute__((ext_vector_type(4)));

// Shared-memory overlay: K1 partition state / cross-chunk scan / chunk params.
// max member ≈ 17.4 KB -> 4 blocks/CU uses ~70 KB of 160 KB LDS.
union SMem {
  struct {
    int   cnt[257];
    int   mode;
    int   ntrue;
    int   sel[MLEN];     // 8 KB
    float e[MLEN];       // 8 KB
  } k1;
  struct {
    float P[CCH];        // 1 KB
    f4    S[CCH];        // 4 KB
  } scan;
  struct {
    float w[TCH];
    float e[TCH];
    float c[TCH];
    int   ls[TCH];
    int   le[TCH];
  } ch;
};

// ---------------------------------------------------------------------------
// K1 body (identical logic to the verified k1_prep, shared-mem via overlay).
// Executed by blocks 0..BSZ-1 of the fused kernel, one block per batch.
// ---------------------------------------------------------------------------
__device__ __forceinline__ void k1_body(
    const int kb, const int tid, SMem& sm,
    const int* __restrict__ bmask_raw, const float* __restrict__ bprob,
    int* __restrict__ Ls, int* __restrict__ Le,
    float* __restrict__ wA, float* __restrict__ eA,
    float* __restrict__ cde, float* __restrict__ Pc)
{
  if (tid == 0) {
    unsigned w0 = ((const unsigned*)bmask_raw)[0];
    sm.k1.mode = (w0 <= 1u) ? 1 : 0;  // 1: int32 per element, 0: uint8
  }
  __syncthreads();
  const int mode = sm.k1.mode;
  const unsigned char* bmask_u8 = (const unsigned char*)bmask_raw;

  const int PER = LFULL / 256;    // 16 positions per thread
  const int base = tid * PER;

  int cnt = 0;
  for (int i = 0; i < PER; ++i) {
    const int L = base + i;
    const int v = mode ? (bmask_raw[kb * LFULL + L] != 0)
                       : (bmask_u8[kb * LFULL + L] != 0);
    cnt += v;
  }
  sm.k1.cnt[tid] = cnt;
  __syncthreads();

  // Exclusive prefix over 256 counts: wave 0, lane i owns entries 4i..4i+3.
  if (tid < 64) {
    const int j = tid * 4;
    const int c0 = sm.k1.cnt[j], c1 = sm.k1.cnt[j + 1];
    const int c2 = sm.k1.cnt[j + 2], c3 = sm.k1.cnt[j + 3];
    const int mysum = c0 + c1 + c2 + c3;
    int incl = mysum;
    #pragma unroll
    for (int off = 1; off < 64; off <<= 1) {
      const int v = __shfl_up(incl, off, 64);
      if (tid >= off) incl += v;
    }
    const int excl = incl - mysum;
    sm.k1.cnt[j]     = excl;
    sm.k1.cnt[j + 1] = excl + c0;
    sm.k1.cnt[j + 2] = excl + c0 + c1;
    sm.k1.cnt[j + 3] = excl + c0 + c1 + c2;
    if (tid == 63) { sm.k1.cnt[256] = incl; sm.k1.ntrue = incl; }
  }
  __syncthreads();
  const int ntrue = sm.k1.ntrue;

  // Fill sel: boundary positions (rank) then non-boundary (ntrue + false-rank)
  int trun = sm.k1.cnt[tid];
  for (int i = 0; i < PER; ++i) {
    const int L = base + i;
    const int v = mode ? (bmask_raw[kb * LFULL + L] != 0)
                       : (bmask_u8[kb * LFULL + L] != 0);
    if (v) {
      if (trun < MLEN) sm.k1.sel[trun] = L;
      ++trun;
    } else {
      const int f = L - trun;           // falses strictly before L
      const int slot = ntrue + f;
      if (slot < MLEN) sm.k1.sel[slot] = L;
    }
  }
  __syncthreads();

  // w, e per selected position
  for (int j = tid; j < MLEN; j += 256) {
    const int L = sm.k1.sel[j];
    float p = bprob[((size_t)kb * LFULL + L) * 2 + 1];
    p = fminf(fmaxf(p, CLIP_EPS), 1.0f - CLIP_EPS);
    const float dt = -log1pf(-p);       // log(1/(1-p))
    wA[kb * MLEN + j] = p / dt;
    const float e = 1.0f - p;           // exp(-dt) exactly
    eA[kb * MLEN + j] = e;
    sm.k1.e[j] = e;
  }
  __syncthreads();

  // per-chunk cumulative decay + chunk product: one thread per chunk of 8
  {
    const int c = tid;                  // 256 chunks
    const int o = c * TCH;
    float run = 1.0f;
    #pragma unroll
    for (int i = 0; i < TCH; ++i) {
      run *= sm.k1.e[o + i];
      cde[kb * MLEN + o + i] = run;
    }
    Pc[kb * CCH + c] = run;
  }

  // scatter ranges: plug[L] = (#boundaries <= L) - 1, clamped to [0, M-1]
  const int nb = (ntrue < MLEN) ? ntrue : MLEN;
  for (int j = tid; j < MLEN; j += 256) {
    int ls, le;
    if (nb == 0) {
      ls = (j == 0) ? 0 : LFULL;
      le = (j == 0) ? LFULL : LFULL;
    } else if (j < nb) {
      ls = (j == 0) ? 0 : sm.k1.sel[j];
      le = (j == nb - 1) ? LFULL : sm.k1.sel[j + 1];
    } else {
      ls = LFULL; le = LFULL;           // empty
    }
    Ls[kb * MLEN + j] = ls;
    Le[kb * MLEN + j] = le;
  }
}

// ---------------------------------------------------------------------------
// Fused cooperative kernel. grid = (2, 256, 2) = 1024 blocks x 256 thr
//   = exactly 4 blocks/CU on 256 CUs (co-residency enforced by
//   __launch_bounds__(256,4): 4 waves/EU -> <=128 VGPR).
// Phase A: issue x loads (regs) for own chunk; blocks 0,1 run K1 under them.
// Phase B: local scan in regs (xr[t] <- running state), write chunk-final S.
// Phase C: blocks re-role to (d4,b); Hillis-Steele cross-chunk scan, G into S.
// Phase D: y[t] = fma(cde[t], G, xr[t]); NT scatter to out rows [Ls,Le).
// hid is read exactly once (was twice).
// ---------------------------------------------------------------------------
__global__ __launch_bounds__(256, 4) void fused_all(
    const float* __restrict__ hid, const int* __restrict__ bmask_raw,
    const float* __restrict__ bprob, float* __restrict__ out,
    int* __restrict__ Ls, int* __restrict__ Le,
    float* __restrict__ wA, float* __restrict__ eA,
    float* __restrict__ cde, float* __restrict__ Pc,
    float* __restrict__ S)
{
  cg::grid_group grid = cg::this_grid();
  const int tid  = threadIdx.x;
  const int dgrp = blockIdx.x;   // [0,2)
  const int c    = blockIdx.y;   // [0,256) chunk
  const int b    = blockIdx.z;   // [0,2)   batch
  const int flat = (int)blockIdx.x +
                   (int)gridDim.x * ((int)blockIdx.y + (int)gridDim.y * (int)blockIdx.z);

  __shared__ SMem sm;

  // ---- Phase A: issue this chunk's x loads; they retire under K1/sync ----
  const int d4 = dgrp * 256 + tid;                    // f4 lane in [0,512)
  const f4* xp = (const f4*)hid + ((size_t)(b * MLEN + c * TCH) * DMODEL >> 2) + d4;
  f4 xr[TCH];
  #pragma unroll
  for (int t = 0; t < TCH; ++t) xr[t] = xp[(size_t)t * (DMODEL / 4)];

  // K1 on blocks 0..BSZ-1 (uniform per block; contains __syncthreads)
  if (flat < BSZ)
    k1_body(flat, tid, sm, bmask_raw, bprob, Ls, Le, wA, eA, cde, Pc);

  __threadfence();
  grid.sync();                                        // #1: K1 outputs visible

  // ---- Phase B: local chunk scan; xr[t] becomes local state; write S ----
  const int o = b * MLEN + c * TCH;
  if (tid < TCH)            sm.ch.w[tid]       = wA[o + tid];
  else if (tid < 2 * TCH)   sm.ch.e[tid - TCH] = eA[o + (tid - TCH)];
  __syncthreads();

  f4 run = {0.f, 0.f, 0.f, 0.f};
  #pragma unroll
  for (int t = 0; t < TCH; ++t) {
    const float w = sm.ch.w[t], e = sm.ch.e[t];
    run.x = fmaf(e, run.x, w * xr[t].x);
    run.y = fmaf(e, run.y, w * xr[t].y);
    run.z = fmaf(e, run.z, w * xr[t].z);
    run.w = fmaf(e, run.w, w * xr[t].w);
    xr[t] = run;                                      // keep per-step state
  }
  f4* Sf4 = (f4*)S;
  Sf4[(size_t)(b * CCH + c) * (DMODEL / 4) + d4] = run;

  __threadfence();
  grid.sync();                                        // #2: chunk states visible

  // ---- Phase C: cross-chunk exclusive scan; block -> (d4 lane, batch) ----
  {
    const int tb  = flat >> 9;                        // batch
    const int td4 = flat & 511;                       // f4 lane
    const int cc  = tid;                              // chunk
    const size_t sidx = (size_t)(tb * CCH + cc) * (DMODEL / 4) + td4;
    sm.scan.P[cc] = Pc[tb * CCH + cc];
    sm.scan.S[cc] = Sf4[sidx];
    __syncthreads();

    #pragma unroll
    for (int d = 1; d < CCH; d <<= 1) {
      float pd = 1.0f;
      f4 sd = {0.f, 0.f, 0.f, 0.f};
      if (cc >= d) { pd = sm.scan.P[cc - d]; sd = sm.scan.S[cc - d]; }
      __syncthreads();
      if (cc >= d) {
        f4 cur = sm.scan.S[cc];
        const float pc = sm.scan.P[cc];
        cur.x = fmaf(pc, sd.x, cur.x);
        cur.y = fmaf(pc, sd.y, cur.y);
        cur.z = fmaf(pc, sd.z, cur.z);
        cur.w = fmaf(pc, sd.w, cur.w);
        sm.scan.S[cc] = cur;
        sm.scan.P[cc] = pc * pd;
      }
      __syncthreads();
    }

    // exclusive shift: carry-in for chunk cc is inclusive scan at cc-1
    f4 g = {0.f, 0.f, 0.f, 0.f};
    if (cc > 0) g = sm.scan.S[cc - 1];
    Sf4[sidx] = g;                                    // in place: G
  }

  __threadfence();
  grid.sync();                                        // #3: carry-ins visible

  // ---- Phase D: y = xr + cde*G, NT scatter to out rows [Ls, Le) ----
  if (tid < TCH)            { sm.ch.c[tid] = cde[o + tid]; }
  else if (tid < 2 * TCH)   { const int t = tid - TCH;     sm.ch.ls[t] = Ls[o + t]; }
  else if (tid < 3 * TCH)   { const int t = tid - 2 * TCH; sm.ch.le[t] = Le[o + t]; }
  __syncthreads();

  const f4 H = Sf4[(size_t)(b * CCH + c) * (DMODEL / 4) + d4];
  f4* op = (f4*)out + ((size_t)b * LFULL * DMODEL >> 2) + d4;

  #pragma unroll
  for (int t = 0; t < TCH; ++t) {
    const float cd = sm.ch.c[t];
    f4 y;
    y.x = fmaf(cd, H.x, xr[t].x);
    y.y = fmaf(cd, H.y, xr[t].y);
    y.z = fmaf(cd, H.z, xr[t].z);
    y.w = fmaf(cd, H.w, xr[t].w);
    const int ls = sm.ch.ls[t], le = sm.ch.le[t];
    for (int L = ls; L < le; ++L) {
      __builtin_nontemporal_store(y, op + (size_t)L * (DMODEL / 4));
    }
  }
}

// ===========================================================================
// Fallback path: the previously-verified 4-kernel pipeline (unchanged).
// Used only if the cooperative launch is rejected synchronously.
// ===========================================================================
__global__ __launch_bounds__(256) void k1_prep(
    const int* __restrict__ bmask_raw, const float* __restrict__ bprob,
    int* __restrict__ Ls, int* __restrict__ Le,
    float* __restrict__ wA, float* __restrict__ eA,
    float* __restrict__ cde, float* __restrict__ Pc)
{
  __shared__ SMem sm;
  k1_body(blockIdx.x, threadIdx.x, sm, bmask_raw, bprob, Ls, Le, wA, eA, cde, Pc);
}

__global__ __launch_bounds__(256) void k2_states(
    const float* __restrict__ hid, const float* __restrict__ wA,
    const float* __restrict__ eA, float* __restrict__ S)
{
  const int tid = threadIdx.x;
  const int c = blockIdx.y;
  const int b = blockIdx.z;

  __shared__ float s_w[TCH], s_e[TCH];
  if (tid < TCH)            s_w[tid]       = wA[b * MLEN + c * TCH + tid];
  else if (tid < 2 * TCH)   s_e[tid - TCH] = eA[b * MLEN + c * TCH + (tid - TCH)];
  __syncthreads();

  const int d4 = blockIdx.x * 256 + tid;
  const f4* xp = (const f4*)hid + ((size_t)(b * MLEN + c * TCH) * DMODEL >> 2) + d4;

  f4 st = {0.f, 0.f, 0.f, 0.f};
  #pragma unroll
  for (int t = 0; t < TCH; ++t) {
    const f4 x = xp[(size_t)t * (DMODEL / 4)];
    const float w = s_w[t], e = s_e[t];
    st.x = fmaf(e, st.x, w * x.x);
    st.y = fmaf(e, st.y, w * x.y);
    st.z = fmaf(e, st.z, w * x.z);
    st.w = fmaf(e, st.w, w * x.w);
  }
  ((f4*)S)[((size_t)(b * CCH + c) * DMODEL >> 2) + d4] = st;
}

__global__ __launch_bounds__(256) void k25_scan(
    const float* __restrict__ Pc, float* __restrict__ S)
{
  const int c  = threadIdx.x;
  const int d4 = blockIdx.x;
  const int b  = blockIdx.y;

  __shared__ float sP[CCH];
  __shared__ f4    sS[CCH];

  f4* Sf4 = (f4*)S;
  const size_t idx = ((size_t)(b * CCH + c) * DMODEL >> 2) + d4;

  sP[c] = Pc[b * CCH + c];
  sS[c] = Sf4[idx];
  __syncthreads();

  #pragma unroll
  for (int dstep = 1; dstep < CCH; dstep <<= 1) {
    float pd = 1.0f;
    f4 sd = {0.f, 0.f, 0.f, 0.f};
    if (c >= dstep) { pd = sP[c - dstep]; sd = sS[c - dstep]; }
    __syncthreads();
    if (c >= dstep) {
      f4 cur = sS[c];
      const float pc = sP[c];
      cur.x = fmaf(pc, sd.x, cur.x);
      cur.y = fmaf(pc, sd.y, cur.y);
      cur.z = fmaf(pc, sd.z, cur.z);
      cur.w = fmaf(pc, sd.w, cur.w);
      sS[c] = cur;
      sP[c] = pc * pd;
    }
    __syncthreads();
  }

  f4 g = {0.f, 0.f, 0.f, 0.f};
  if (c > 0) g = sS[c - 1];
  Sf4[idx] = g;
}

__global__ __launch_bounds__(256) void k3_out(
    const float* __restrict__ hid, const float* __restrict__ wA,
    const float* __restrict__ eA, const float* __restrict__ cde,
    const float* __restrict__ G,
    const int* __restrict__ Ls, const int* __restrict__ Le,
    float* __restrict__ out)
{
  const int tid = threadIdx.x;
  const int c = blockIdx.y;
  const int b = blockIdx.z;

  __shared__ float s_w[TCH], s_e[TCH], s_c[TCH];
  __shared__ int   s_ls[TCH], s_le[TCH];
  const int o = b * MLEN + c * TCH;
  if (tid < TCH)          { s_w[tid] = wA[o + tid];  s_ls[tid] = Ls[o + tid]; }
  else if (tid < 2 * TCH) { const int t = tid - TCH;     s_e[t] = eA[o + t]; s_le[t] = Le[o + t]; }
  else if (tid < 3 * TCH) { const int t = tid - 2 * TCH; s_c[t] = cde[o + t]; }
  __syncthreads();

  const int d4 = blockIdx.x * 256 + tid;

  const f4 H = ((const f4*)G)[((size_t)(b * CCH + c) * DMODEL >> 2) + d4];

  const f4* xp = (const f4*)hid + ((size_t)(b * MLEN + c * TCH) * DMODEL >> 2) + d4;
  f4*       op = (f4*)out + ((size_t)b * LFULL * DMODEL >> 2) + d4;

  f4 st = {0.f, 0.f, 0.f, 0.f};
  #pragma unroll
  for (int t = 0; t < TCH; ++t) {
    const f4 x = xp[(size_t)t * (DMODEL / 4)];
    const float w = s_w[t], e = s_e[t], cd = s_c[t];
    st.x = fmaf(e, st.x, w * x.x);
    st.y = fmaf(e, st.y, w * x.y);
    st.z = fmaf(e, st.z, w * x.z);
    st.w = fmaf(e, st.w, w * x.w);
    f4 y;
    y.x = fmaf(cd, H.x, st.x);
    y.y = fmaf(cd, H.y, st.y);
    y.z = fmaf(cd, H.z, st.z);
    y.w = fmaf(cd, H.w, st.w);
    const int ls = s_ls[t], le = s_le[t];
    for (int L = ls; L < le; ++L) {
      __builtin_nontemporal_store(y, op + (size_t)L * (DMODEL / 4));
    }
  }
}

// ---------------------------------------------------------------------------
extern "C" void kernel_launch(void* const* d_in, const int* in_sizes, int n_in,
                              void* d_out, int out_size, void* d_ws, size_t ws_size,
                              hipStream_t stream) {
  const float* hid   = (const float*)d_in[0];   // (2, 2048, 2048) fp32
  const int*   bmask = (const int*)d_in[1];     // (2, 4096) bool (layout sniffed)
  const float* bprob = (const float*)d_in[2];   // (2, 4096, 2) fp32
  float*       out   = (float*)d_out;           // (2, 4096, 2048) fp32

  char* ws = (char*)d_ws;
  const size_t SZI = (size_t)BSZ * MLEN * sizeof(int);    // 16 KB
  const size_t SZF = (size_t)BSZ * MLEN * sizeof(float);  // 16 KB
  int*   Ls  = (int*)(ws);
  int*   Le  = (int*)(ws + SZI);
  float* wA  = (float*)(ws + 2 * SZI);
  float* eA  = (float*)(ws + 2 * SZI + SZF);
  float* cde = (float*)(ws + 2 * SZI + 2 * SZF);
  float* Pc  = (float*)(ws + 2 * SZI + 3 * SZF);          // 2 KB used
  float* S   = (float*)(ws + 2 * SZI + 3 * SZF + 4096);   // 4 MB (S, then G in place)

  dim3 grid(DMODEL / 1024, CCH, BSZ);   // (2, 256, 2) = 1024 blocks
  dim3 block(256);

  void* args[] = { (void*)&hid, (void*)&bmask, (void*)&bprob, (void*)&out,
                   (void*)&Ls, (void*)&Le, (void*)&wA, (void*)&eA,
                   (void*)&cde, (void*)&Pc, (void*)&S };

  hipError_t err = hipLaunchCooperativeKernel((const void*)fused_all, grid, block,
                                              args, 0u, stream);
  if (err != hipSuccess) {
    (void)hipGetLastError();   // clear sticky error; use verified 4-kernel path
    k1_prep<<<dim3(BSZ), block, 0, stream>>>(bmask, bprob, Ls, Le, wA, eA, cde, Pc);
    k2_states<<<grid, block, 0, stream>>>(hid, wA, eA, S);
    k25_scan<<<dim3(DMODEL / 4, BSZ), block, 0, stream>>>(Pc, S);
    k3_out<<<grid, block, 0, stream>>>(hid, wA, eA, cde, S, Ls, Le, out);
  }
}

// Round 2
// 133.733 us; speedup vs baseline: 5.7174x; 5.7174x over previous
//
#include <hip/hip_runtime.h>
#include <math.h>

// Problem constants (fixed by setup_inputs)
#define BSZ    2
#define LFULL  4096
#define MLEN   2048      // M = hidden_states.shape[1]
#define DMODEL 2048
#define CLIP_EPS 1e-4f
#define CCH    256       // number of chunks
#define TCH    8         // chunk length; CCH*TCH == MLEN

// hid prefetch geometry: 2*2048*2048 floats = 2097152 f4 vectors
#define PREF_BLOCKS 1024
#define PREF_PER_BLK 2048          // f4 per prefetch block (2048*16B = 32 KB)

typedef float f4 __attribute__((ext_vector_type(4)));

// ---------------------------------------------------------------------------
// K1 body: boundary-mask stable partition + per-position decay params.
//  - sniff boundary_mask dtype (int32 words vs packed uint8)
//  - sel[j] = j-th boundary position, then non-boundary positions in order
//  - p -> w = p/dt (dt = -log1p(-p)), e = 1-p  (== exp(-dt) exactly)
//  - per-chunk inclusive cumulative decay cde, chunk products Pc
//  - output scatter ranges [Ls[t], Le[t])
// ---------------------------------------------------------------------------
__device__ __forceinline__ void k1_body(
    const int b, const int tid,
    const int* __restrict__ bmask_raw, const float* __restrict__ bprob,
    int* __restrict__ Ls, int* __restrict__ Le,
    float* __restrict__ wA, float* __restrict__ eA,
    float* __restrict__ cde, float* __restrict__ Pc,
    int* s_cnt /*257*/, int* s_meta /*2: mode,ntrue*/, int* s_sel /*MLEN*/,
    float* s_e /*MLEN*/)
{
  if (tid == 0) {
    unsigned w0 = ((const unsigned*)bmask_raw)[0];
    s_meta[0] = (w0 <= 1u) ? 1 : 0;  // 1: int32 per element, 0: uint8
  }
  __syncthreads();
  const int mode = s_meta[0];
  const unsigned char* bmask_u8 = (const unsigned char*)bmask_raw;

  const int PER = LFULL / 256;    // 16 positions per thread
  const int base = tid * PER;

  int cnt = 0;
  for (int i = 0; i < PER; ++i) {
    const int L = base + i;
    const int v = mode ? (bmask_raw[b * LFULL + L] != 0)
                       : (bmask_u8[b * LFULL + L] != 0);
    cnt += v;
  }
  s_cnt[tid] = cnt;
  __syncthreads();

  // Exclusive prefix over 256 counts: wave 0, lane i owns entries 4i..4i+3.
  if (tid < 64) {
    const int j = tid * 4;
    const int c0 = s_cnt[j], c1 = s_cnt[j + 1], c2 = s_cnt[j + 2], c3 = s_cnt[j + 3];
    const int mysum = c0 + c1 + c2 + c3;
    int incl = mysum;
    #pragma unroll
    for (int off = 1; off < 64; off <<= 1) {
      const int v = __shfl_up(incl, off, 64);
      if (tid >= off) incl += v;
    }
    const int excl = incl - mysum;
    s_cnt[j]     = excl;
    s_cnt[j + 1] = excl + c0;
    s_cnt[j + 2] = excl + c0 + c1;
    s_cnt[j + 3] = excl + c0 + c1 + c2;
    if (tid == 63) { s_cnt[256] = incl; s_meta[1] = incl; }
  }
  __syncthreads();
  const int ntrue = s_meta[1];

  // Fill sel: boundary positions (rank) then non-boundary (ntrue + false-rank)
  int trun = s_cnt[tid];
  for (int i = 0; i < PER; ++i) {
    const int L = base + i;
    const int v = mode ? (bmask_raw[b * LFULL + L] != 0)
                       : (bmask_u8[b * LFULL + L] != 0);
    if (v) {
      if (trun < MLEN) s_sel[trun] = L;
      ++trun;
    } else {
      const int f = L - trun;           // falses strictly before L
      const int slot = ntrue + f;
      if (slot < MLEN) s_sel[slot] = L;
    }
  }
  __syncthreads();

  // w, e per selected position
  for (int j = tid; j < MLEN; j += 256) {
    const int L = s_sel[j];
    float p = bprob[((size_t)b * LFULL + L) * 2 + 1];
    p = fminf(fmaxf(p, CLIP_EPS), 1.0f - CLIP_EPS);
    const float dt = -log1pf(-p);       // log(1/(1-p))
    wA[b * MLEN + j] = p / dt;
    const float e = 1.0f - p;           // exp(-dt) exactly
    eA[b * MLEN + j] = e;
    s_e[j] = e;
  }
  __syncthreads();

  // per-chunk cumulative decay + chunk product: one thread per chunk of 8
  {
    const int c = tid;                  // 256 chunks
    const int o = c * TCH;
    float run = 1.0f;
    #pragma unroll
    for (int i = 0; i < TCH; ++i) {
      run *= s_e[o + i];
      cde[b * MLEN + o + i] = run;
    }
    Pc[b * CCH + c] = run;
  }

  // scatter ranges: plug[L] = (#boundaries <= L) - 1, clamped to [0, M-1]
  const int nb = (ntrue < MLEN) ? ntrue : MLEN;
  for (int j = tid; j < MLEN; j += 256) {
    int ls, le;
    if (nb == 0) {
      ls = (j == 0) ? 0 : LFULL;
      le = (j == 0) ? LFULL : LFULL;
    } else if (j < nb) {
      ls = (j == 0) ? 0 : s_sel[j];
      le = (j == nb - 1) ? LFULL : s_sel[j + 1];
    } else {
      ls = LFULL; le = LFULL;           // empty
    }
    Ls[b * MLEN + j] = ls;
    Le[b * MLEN + j] = le;
  }
}

// ---------------------------------------------------------------------------
// K1 + hid prefetch. Blocks 0..BSZ-1 run the (latency-bound) prep on 2 CUs;
// blocks BSZ.. stream all of hid with plain cache-allocating loads so it
// lands in the memory-side 256 MiB Infinity Cache (shared across XCDs).
// K2/K3's hid reads then hit L3 instead of cold HBM. The prefetch runs
// entirely under K1's latency, so it is ~free.
// ---------------------------------------------------------------------------
__global__ __launch_bounds__(256) void k1_prep(
    const int* __restrict__ bmask_raw, const float* __restrict__ bprob,
    const float* __restrict__ hid,
    int* __restrict__ Ls, int* __restrict__ Le,
    float* __restrict__ wA, float* __restrict__ eA,
    float* __restrict__ cde, float* __restrict__ Pc)
{
  const int blk = blockIdx.x;
  const int tid = threadIdx.x;

  if (blk >= BSZ) {
    // ---- prefetch role: 1024 blocks x 256 thr x 8 f4 = 33.5 MB ----
    const int p = blk - BSZ;
    const f4* hp = (const f4*)hid + (size_t)p * PREF_PER_BLK + tid;
    f4 acc = {0.f, 0.f, 0.f, 0.f};
    #pragma unroll
    for (int i = 0; i < PREF_PER_BLK / 256; ++i) {
      const f4 v = hp[i * 256];
      acc.x += v.x; acc.y += v.y; acc.z += v.z; acc.w += v.w;
    }
    // keep the loads live without any store (rule #17 sink)
    asm volatile("" :: "v"(acc.x), "v"(acc.y), "v"(acc.z), "v"(acc.w));
    return;
  }

  __shared__ int   s_cnt[257];
  __shared__ int   s_meta[2];
  __shared__ int   s_sel[MLEN];        // 8 KB
  __shared__ float s_e[MLEN];          // 8 KB
  k1_body(blk, tid, bmask_raw, bprob, Ls, Le, wA, eA, cde, Pc,
          s_cnt, s_meta, s_sel, s_e);
}

// ---------------------------------------------------------------------------
// K2: per-chunk local scan (zero init) -> chunk-final state S[b][c][d]
// grid: (DMODEL/1024, CCH, BSZ) = (2, 256, 2) = 1024 blocks, float4/thread
// ---------------------------------------------------------------------------
__global__ __launch_bounds__(256) void k2_states(
    const float* __restrict__ hid, const float* __restrict__ wA,
    const float* __restrict__ eA, float* __restrict__ S)
{
  const int tid = threadIdx.x;
  const int c = blockIdx.y;
  const int b = blockIdx.z;

  __shared__ float s_w[TCH], s_e[TCH];
  if (tid < TCH)            s_w[tid]       = wA[b * MLEN + c * TCH + tid];
  else if (tid < 2 * TCH)   s_e[tid - TCH] = eA[b * MLEN + c * TCH + (tid - TCH)];
  __syncthreads();

  const int d4 = blockIdx.x * 256 + tid;       // float4 lane in [0, 512)
  const f4* xp = (const f4*)hid + ((size_t)(b * MLEN + c * TCH) * DMODEL >> 2) + d4;

  f4 st = {0.f, 0.f, 0.f, 0.f};
  #pragma unroll
  for (int t = 0; t < TCH; ++t) {
    const f4 x = xp[(size_t)t * (DMODEL / 4)];
    const float w = s_w[t], e = s_e[t];
    st.x = fmaf(e, st.x, w * x.x);
    st.y = fmaf(e, st.y, w * x.y);
    st.z = fmaf(e, st.z, w * x.z);
    st.w = fmaf(e, st.w, w * x.w);
  }
  ((f4*)S)[((size_t)(b * CCH + c) * DMODEL >> 2) + d4] = st;
}

// ---------------------------------------------------------------------------
// K2.5: cross-chunk exclusive scan, in place over S.
// grid: (DMODEL/4, BSZ) = (512, 2) = 1024 blocks; 256 threads = 256 chunks
// ---------------------------------------------------------------------------
__global__ __launch_bounds__(256) void k25_scan(
    const float* __restrict__ Pc, float* __restrict__ S)
{
  const int c  = threadIdx.x;   // chunk index
  const int d4 = blockIdx.x;    // float4 lane in [0, DMODEL/4)
  const int b  = blockIdx.y;

  __shared__ float sP[CCH];
  __shared__ f4    sS[CCH];

  f4* Sf4 = (f4*)S;
  const size_t idx = ((size_t)(b * CCH + c) * DMODEL >> 2) + d4;

  sP[c] = Pc[b * CCH + c];
  sS[c] = Sf4[idx];
  __syncthreads();

  #pragma unroll
  for (int dstep = 1; dstep < CCH; dstep <<= 1) {
    float pd = 1.0f;
    f4 sd = {0.f, 0.f, 0.f, 0.f};
    if (c >= dstep) { pd = sP[c - dstep]; sd = sS[c - dstep]; }
    __syncthreads();
    if (c >= dstep) {
      f4 cur = sS[c];
      const float pc = sP[c];
      cur.x = fmaf(pc, sd.x, cur.x);
      cur.y = fmaf(pc, sd.y, cur.y);
      cur.z = fmaf(pc, sd.z, cur.z);
      cur.w = fmaf(pc, sd.w, cur.w);
      sS[c] = cur;
      sP[c] = pc * pd;
    }
    __syncthreads();
  }

  // exclusive shift: carry-in for chunk c is inclusive scan at c-1
  f4 g = {0.f, 0.f, 0.f, 0.f};
  if (c > 0) g = sS[c - 1];
  Sf4[idx] = g;
}

// ---------------------------------------------------------------------------
// K3: load carry-in G, redo local scan (hid now L3-hot), y = local + cde*G,
//     scatter to out rows [Ls, Le). Non-temporal stores (write-only 67 MB).
// grid: (2, CCH, BSZ) = 1024 blocks
// ---------------------------------------------------------------------------
__global__ __launch_bounds__(256) void k3_out(
    const float* __restrict__ hid, const float* __restrict__ wA,
    const float* __restrict__ eA, const float* __restrict__ cde,
    const float* __restrict__ G,
    const int* __restrict__ Ls, const int* __restrict__ Le,
    float* __restrict__ out)
{
  const int tid = threadIdx.x;
  const int c = blockIdx.y;
  const int b = blockIdx.z;

  __shared__ float s_w[TCH], s_e[TCH], s_c[TCH];
  __shared__ int   s_ls[TCH], s_le[TCH];
  const int o = b * MLEN + c * TCH;
  if (tid < TCH)          { s_w[tid] = wA[o + tid];  s_ls[tid] = Ls[o + tid]; }
  else if (tid < 2 * TCH) { const int t = tid - TCH;     s_e[t] = eA[o + t]; s_le[t] = Le[o + t]; }
  else if (tid < 3 * TCH) { const int t = tid - 2 * TCH; s_c[t] = cde[o + t]; }
  __syncthreads();

  const int d4 = blockIdx.x * 256 + tid;

  const f4 H = ((const f4*)G)[((size_t)(b * CCH + c) * DMODEL >> 2) + d4];

  const f4* xp = (const f4*)hid + ((size_t)(b * MLEN + c * TCH) * DMODEL >> 2) + d4;
  f4*       op = (f4*)out + ((size_t)b * LFULL * DMODEL >> 2) + d4;

  f4 st = {0.f, 0.f, 0.f, 0.f};
  #pragma unroll
  for (int t = 0; t < TCH; ++t) {
    const f4 x = xp[(size_t)t * (DMODEL / 4)];
    const float w = s_w[t], e = s_e[t], cd = s_c[t];
    st.x = fmaf(e, st.x, w * x.x);
    st.y = fmaf(e, st.y, w * x.y);
    st.z = fmaf(e, st.z, w * x.z);
    st.w = fmaf(e, st.w, w * x.w);
    f4 y;
    y.x = fmaf(cd, H.x, st.x);
    y.y = fmaf(cd, H.y, st.y);
    y.z = fmaf(cd, H.z, st.z);
    y.w = fmaf(cd, H.w, st.w);
    const int ls = s_ls[t], le = s_le[t];
    for (int L = ls; L < le; ++L) {
      __builtin_nontemporal_store(y, op + (size_t)L * (DMODEL / 4));
    }
  }
}

// ---------------------------------------------------------------------------
extern "C" void kernel_launch(void* const* d_in, const int* in_sizes, int n_in,
                              void* d_out, int out_size, void* d_ws, size_t ws_size,
                              hipStream_t stream) {
  const float* hid   = (const float*)d_in[0];   // (2, 2048, 2048) fp32
  const int*   bmask = (const int*)d_in[1];     // (2, 4096) bool (layout sniffed)
  const float* bprob = (const float*)d_in[2];   // (2, 4096, 2) fp32
  float*       out   = (float*)d_out;           // (2, 4096, 2048) fp32

  char* ws = (char*)d_ws;
  const size_t SZI = (size_t)BSZ * MLEN * sizeof(int);    // 16 KB
  const size_t SZF = (size_t)BSZ * MLEN * sizeof(float);  // 16 KB
  int*   Ls  = (int*)(ws);
  int*   Le  = (int*)(ws + SZI);
  float* wA  = (float*)(ws + 2 * SZI);
  float* eA  = (float*)(ws + 2 * SZI + SZF);
  float* cde = (float*)(ws + 2 * SZI + 2 * SZF);
  float* Pc  = (float*)(ws + 2 * SZI + 3 * SZF);          // 2 KB used
  float* S   = (float*)(ws + 2 * SZI + 3 * SZF + 4096);   // 4 MB (S, then G in place)

  // K1 (2 blocks) + hid->L3 prefetch (1024 blocks) overlapped
  k1_prep<<<dim3(BSZ + PREF_BLOCKS), dim3(256), 0, stream>>>(
      bmask, bprob, hid, Ls, Le, wA, eA, cde, Pc);

  dim3 grid(DMODEL / 1024, CCH, BSZ);   // (2, 256, 2) = 1024 blocks
  k2_states<<<grid, dim3(256), 0, stream>>>(hid, wA, eA, S);

  k25_scan<<<dim3(DMODEL / 4, BSZ), dim3(256), 0, stream>>>(Pc, S);

  k3_out<<<grid, dim3(256), 0, stream>>>(hid, wA, eA, cde, S, Ls, Le, out);
}